// Round 2
// baseline (561.441 us; speedup 1.0000x reference)
//
#include <hip/hip_runtime.h>

#define B_ 32
#define T_ 400
#define C_ 3000
#define SN_ 128
#define SD_ 512
#define LNS 8.94637462f    // ln(64*120)
#define LN120 4.78749174f  // ln(120)
#define SPANB 48           // byte stride between 32-byte spans in LDS (16-aligned, 2-way banks = free)

__device__ __forceinline__ float clip30(float v) { return fminf(30.f, fmaxf(-30.f, v)); }

__device__ __forceinline__ int dot4i8(unsigned a, unsigned b, int c) {
#if __has_builtin(__builtin_amdgcn_sdot4)
    return __builtin_amdgcn_sdot4((int)a, (int)b, c, false);
#else
    return c + (int)(a & 0xff) * (int)(b & 0xff)
             + (int)((a >> 8) & 0xff) * (int)((b >> 8) & 0xff)
             + (int)((a >> 16) & 0xff) * (int)((b >> 16) & 0xff)
             + (int)((a >> 24) & 0xff) * (int)((b >> 24) & 0xff);
#endif
}

template <int CTRL>
__device__ __forceinline__ int dpp_i(int v) {
    return __builtin_amdgcn_update_dpp(v, v, CTRL, 0xF, 0xF, false);
}
template <int CTRL>
__device__ __forceinline__ float fmaxdpp(float v) {
    int mv = __builtin_amdgcn_update_dpp(__float_as_int(v), __float_as_int(v), CTRL, 0xF, 0xF, false);
    return fmaxf(v, __int_as_float(mv));
}
template <int CTRL>
__device__ __forceinline__ float faddpp(float v) {
    int mv = __builtin_amdgcn_update_dpp(__float_as_int(v), __float_as_int(v), CTRL, 0xF, 0xF, false);
    return v + __int_as_float(mv);
}
// a += partner-lane's b; CTRL: quad_perm xor1=0xB1 xor2=0x4E, ROW_XMASK xor_k = 0x120|k
template <int CTRL>
__device__ __forceinline__ float fxaddf(float a, float b) {
    int t = __builtin_amdgcn_update_dpp(__float_as_int(b), __float_as_int(b), CTRL, 0xF, 0xF, false);
    return a + __int_as_float(t);
}
__device__ __forceinline__ float swz16f(float v) {
    return __int_as_float(__builtin_amdgcn_ds_swizzle(__float_as_int(v), 0x401F));
}
__device__ __forceinline__ float waveallmax(float v) {
    v = fmaxdpp<0x121>(v); v = fmaxdpp<0x122>(v);
    v = fmaxdpp<0x124>(v); v = fmaxdpp<0x128>(v);
    v = fmaxf(v, swz16f(v));
    v = fmaxf(v, __shfl_xor(v, 32, 64));
    return v;
}
__device__ __forceinline__ float waveallsum(float v) {
    v = faddpp<0x121>(v); v = faddpp<0x122>(v);
    v = faddpp<0x124>(v); v = faddpp<0x128>(v);
    v = v + swz16f(v);
    v = v + __shfl_xor(v, 32, 64);
    return v;
}

// prep:
//  [0,65536) dwords: exp(den_trans) i8 (scale 64) in the per-thread dot4 layout
//    for the 1024-thread / half-split / 8-span decomposition.
//    dword o: b4=o&3, tid=(o>>2)&1023, k=o>>12; reg r=4k+b4 (0..63);
//    slot m=r>>3, i=r&7; g=tid>>4, h=(tid>>3)&1, j=tid&7;
//    col s_out = 8g + (m^j)  (XOR-slot for select-free butterfly);
//    src s_from = 256h + 32j + 4i + by.
//    fwd reads uint4 #k at tg[(k<<10)+tid] -> tq[4k+b4]=dword o.
//  [65536,+6553600) em_den[b][t][s] pre-clipped; then em_num[b][t][s].
__global__ void prep(const float* __restrict__ dt, unsigned* __restrict__ tp8,
                     const float* __restrict__ x, const int* __restrict__ den_pdf,
                     const int* __restrict__ num_pdf,
                     float* __restrict__ em_den, float* __restrict__ em_num) {
    size_t id = (size_t)blockIdx.x * 1024 + threadIdx.x;
    if (id < 65536) {
        int o = (int)id;
        int b4 = o & 3, tid = (o >> 2) & 1023, k = o >> 12;
        int r = 4 * k + b4;
        int m = r >> 3, i = r & 7;
        int g = tid >> 4, h = (tid >> 3) & 1, j = tid & 7;
        int s_out = 8 * g + (m ^ j);
        int s_from0 = 256 * h + 32 * j + 4 * i;
        unsigned wv = 0;
        #pragma unroll
        for (int by = 0; by < 4; ++by) {
            float e = __expf(dt[(s_from0 + by) * SD_ + s_out]);
            int pq = __float2int_rn(e * 64.f);
            if (pq > 127) pq = 127;
            wv |= (unsigned)pq << (8 * by);
        }
        tp8[o] = wv;
    } else if (id < 65536 + 6553600) {
        size_t e = id - 65536;
        int s = (int)(e & 511);
        size_t bt = e >> 9;                    // b*400 + t
        em_den[e] = clip30(x[bt * C_ + den_pdf[s]]);
    } else if (id < 65536 + 6553600 + 1638400) {
        size_t e = id - 65536 - 6553600;
        int s = (int)(e & 127);
        size_t bt = e >> 7;
        int b = (int)(bt / 400);
        em_num[e] = clip30(x[bt * C_ + num_pdf[b * SN_ + s]]);
    }
}

__global__ __launch_bounds__(1024, 4)
void fwd_kernel(const int* __restrict__ seqlen,
                const float* __restrict__ num_trans,
                const float* __restrict__ num_init, const float* __restrict__ num_final,
                const unsigned* __restrict__ tp8,
                const float* __restrict__ den_init, const float* __restrict__ den_final,
                const float* __restrict__ em_den, const float* __restrict__ em_num,
                float* __restrict__ parts) {
    const int tid = threadIdx.x;

    if (blockIdx.x < B_) {
        // ---- denominator: one batch/WG, 1024 threads (16 waves, 4/SIMD).
        // Each state s = 8*(tid>>4)+(tid&7) handled by 2 threads (halves
        // h=(tid>>3)&1 of the 512-source dot, 64 dot4 each). Per-wave
        // log-scales Ms[w] (wave w owns states [32w,32w+32)). Lane reads one
        // 32B span (2 x b128), 8 partial dots (slot m = state 8g+(m^j)),
        // 4-stage XOR butterfly (xor1,2,4 over j; xor8 over h) -> full dot. ----
        __shared__ __align__(16) unsigned char ea[2][16 * SPANB];   // u8 acts, dbuf
        __shared__ float Ms[2][16];                                 // per-wave log scales
        __shared__ float fr[16];
        const int b = blockIdx.x;
        const int L = seqlen[b];
        const int w = tid >> 6, l = tid & 63;   // wave, lane
        const int hj = tid & 15;                // source span id = 8h + j
        const int s = 8 * (tid >> 4) + (tid & 7);   // own state
        const int wra = SPANB * (s >> 5) + (s & 31);  // writer byte addr (j&3==0,h==0 lanes)
        const bool wrt = ((tid & 0xB) == 0);    // h==0 && (j&3)==0

        // trans: slot m, dword i -> tq[8m+i] = T8[256h+32j+4i+b, 8g+(m^j)], pinned
        unsigned tq[64];
        {
            const uint4* tg = (const uint4*)tp8;
            #pragma unroll
            for (int k = 0; k < 16; ++k) {
                uint4 v = tg[(k << 10) + tid];
                asm volatile("v_mov_b32 %0, %1" : "=v"(tq[4 * k + 0]) : "v"(v.x));
                asm volatile("v_mov_b32 %0, %1" : "=v"(tq[4 * k + 1]) : "v"(v.y));
                asm volatile("v_mov_b32 %0, %1" : "=v"(tq[4 * k + 2]) : "v"(v.z));
                asm volatile("v_mov_b32 %0, %1" : "=v"(tq[4 * k + 3]) : "v"(v.w));
            }
        }

        const float* emp = em_den + (size_t)b * T_ * SD_ + s;

        // t = 0: alpha0 = init + em0; quantize vs wave-local max
        float a0f = den_init[s] + emp[0];
        float gw = waveallmax(a0f);
        int un = __float2int_rn(120.f * __expf(a0f - gw));
        if (un > 127) un = 127;
        {
            int uu = un;
            uu |= dpp_i<0xB1>(uu) << 8;
            uu |= dpp_i<0x4E>(uu) << 16;
            if (wrt) *(unsigned*)&ea[0][wra] = (unsigned)uu;
        }
        if (l == 0) Ms[0][w] = gw;
        __syncthreads();

        float emA = emp[SD_], emB = emp[2 * SD_];
        int cur = 0;
        for (int t = 1; t < L; ++t) {
            int tn = (t + 2 < L) ? t + 2 : L - 1;
            float emN = emp[(size_t)tn * SD_];

            float ms_j = Ms[cur][hj];           // source span's wave scale
            float ms_w = Ms[cur][w];            // own wave's (reference) scale
            const uint4* er = (const uint4*)&ea[cur][SPANB * hj];
            uint4 e0 = er[0], e1 = er[1];

            int ac0 = 0, ac1 = 0, ac2 = 0, ac3 = 0;
            int ac4 = 0, ac5 = 0, ac6 = 0, ac7 = 0;
            #define DOTD(W, I) \
                ac0 = dot4i8((W), tq[(I)],      ac0); \
                ac1 = dot4i8((W), tq[8 + (I)],  ac1); \
                ac2 = dot4i8((W), tq[16 + (I)], ac2); \
                ac3 = dot4i8((W), tq[24 + (I)], ac3); \
                ac4 = dot4i8((W), tq[32 + (I)], ac4); \
                ac5 = dot4i8((W), tq[40 + (I)], ac5); \
                ac6 = dot4i8((W), tq[48 + (I)], ac6); \
                ac7 = dot4i8((W), tq[56 + (I)], ac7);
            DOTD(e0.x, 0) DOTD(e0.y, 1) DOTD(e0.z, 2) DOTD(e0.w, 3)
            DOTD(e1.x, 4) DOTD(e1.y, 5) DOTD(e1.z, 6) DOTD(e1.w, 7)
            #undef DOTD

            // scale by own span's factor, then select-free XOR butterfly fold
            float e_own = __expf(ms_j - ms_w);
            float f0 = (float)ac0 * e_own, f1 = (float)ac1 * e_own;
            float f2 = (float)ac2 * e_own, f3 = (float)ac3 * e_own;
            float f4 = (float)ac4 * e_own, f5 = (float)ac5 * e_own;
            float f6 = (float)ac6 * e_own, f7 = (float)ac7 * e_own;
            f0 = fxaddf<0x121>(f0, f1);  f2 = fxaddf<0x121>(f2, f3);
            f4 = fxaddf<0x121>(f4, f5);  f6 = fxaddf<0x121>(f6, f7);
            f0 = fxaddf<0x122>(f0, f2);  f4 = fxaddf<0x122>(f4, f6);
            f0 = fxaddf<0x124>(f0, f4);
            f0 = fxaddf<0x128>(f0, f0);  // fold halves h -> full dot for state s

            // approx ln via float bits (underestimates <=0.06 nats; moves quant point only)
            float g = fmaf(0.69314718f,
                           (float)__float_as_int(f0) * 1.1920929e-7f - 127.0f, emA);
            float gg = waveallmax(g);   // max over own wave's 32 states
            un = __float2int_rn(120.f * f0 * __expf(emA - gg));
            if (un > 127) un = 127;
            {
                int uu = un;
                uu |= dpp_i<0xB1>(uu) << 8;
                uu |= dpp_i<0x4E>(uu) << 16;
                if (wrt) *(unsigned*)&ea[cur ^ 1][wra] = (unsigned)uu;
            }
            if (l == 0) Ms[cur ^ 1][w] = gg + ms_w - LNS;
            emA = emB; emB = emN;
            __syncthreads();            // single barrier per step (dbuf'd ea + Ms)
            cur ^= 1;
        }

        // final: alpha(s) = log(u_s) + Ms[w(s)] - ln120; states duplicated x2 (h) -> mask h==0
        float msw = Ms[cur][w];
        float mm = Ms[cur][0];
        #pragma unroll
        for (int k2 = 1; k2 < 16; ++k2) mm = fmaxf(mm, Ms[cur][k2]);
        float fv = ((tid & 8) == 0) ? (float)un * __expf(den_final[s] + (msw - mm)) : 0.f;
        fv = waveallsum(fv);
        if (l == 0) fr[w] = fv;
        __syncthreads();
        if (tid == 0) {
            float tot = 0.f;
            for (int i = 0; i < 16; ++i) tot += fr[i];
            parts[B_ + b] = mm + __logf(tot) - LN120;
        }
    } else {
        // ---- numerator: 8 banded 128-state chains per 1024-thread WG
        //      (proven path; double-buffered -> 1 barrier/step) ----
        __shared__ float aLn[2][8][SN_];
        __shared__ float nredn[8][2];
        const int nb = blockIdx.x - B_;               // 0..3
        const int lb = tid >> 7;                      // local batch 0..7
        const int b  = nb * 8 + lb;
        const int s  = tid & 127;
        const int L  = seqlen[b];
        const int lane = tid & 63;
        const int wv2 = (tid >> 6) & 1;
        const float* ep = em_num + (size_t)b * T_ * SN_ + s;
        const float tself = num_trans[((size_t)b * SN_ + s) * SN_ + s];
        const float tup = (s > 0) ? num_trans[((size_t)b * SN_ + (s - 1)) * SN_ + s] : 0.f;
        float alpha = num_init[b * SN_ + s] + ep[0];
        aLn[0][lb][s] = alpha;
        __syncthreads();
        float emA = ep[SN_], emB = ep[2 * SN_];
        int cur = 0;
        for (int t = 1; t < T_; ++t) {
            int tt = t + 2; if (tt > T_ - 1) tt = T_ - 1;
            float emN = ep[(size_t)tt * SN_];
            bool live = (t < L);
            float yy = alpha + tself;
            float newa;
            if (s > 0) {
                float xx = aLn[cur][lb][s - 1] + tup;
                float mx = fmaxf(xx, yy), mn = fminf(xx, yy);
                newa = mx + log1pf(__expf(mn - mx)) + emA;
            } else {
                newa = yy + emA;
            }
            if (live) alpha = newa;
            aLn[cur ^ 1][lb][s] = alpha;
            emA = emB; emB = emN;
            __syncthreads();
            cur ^= 1;
        }
        float v = alpha + num_final[b * SN_ + s];
        float wm = v;
        #pragma unroll
        for (int o = 32; o; o >>= 1) wm = fmaxf(wm, __shfl_xor(wm, o, 64));
        if (lane == 0) nredn[lb][wv2] = wm;
        __syncthreads();
        float fm = fmaxf(nredn[lb][0], nredn[lb][1]);
        __syncthreads();
        float pe = __expf(v - fm);
        #pragma unroll
        for (int o = 32; o; o >>= 1) pe += __shfl_xor(pe, o, 64);
        if (lane == 0) nredn[lb][wv2] = pe;
        __syncthreads();
        if (s == 0) parts[b] = fm + __logf(nredn[lb][0] + nredn[lb][1]);
    }
}

__global__ void finish(const float* __restrict__ parts, float* __restrict__ out) {
    int lane = threadIdx.x;   // 64 threads, 1 wave
    float v = (lane < B_) ? (parts[B_ + lane] - parts[lane]) : 0.f;
    #pragma unroll
    for (int o = 32; o; o >>= 1) v += __shfl_xor(v, o, 64);
    if (lane == 0) out[0] = v;   // loss = sum(den) - sum(num)
}

extern "C" void kernel_launch(void* const* d_in, const int* in_sizes, int n_in,
                              void* d_out, int out_size, void* d_ws, size_t ws_size,
                              hipStream_t stream) {
    const float* x         = (const float*)d_in[0];
    const int*   seqlen    = (const int*)d_in[1];
    const float* num_trans = (const float*)d_in[2];
    const int*   num_pdf   = (const int*)d_in[3];
    const float* num_init  = (const float*)d_in[4];
    const float* num_final = (const float*)d_in[5];
    const float* den_trans = (const float*)d_in[6];
    const int*   den_pdf   = (const int*)d_in[7];
    const float* den_init  = (const float*)d_in[8];
    const float* den_final = (const float*)d_in[9];
    float* out   = (float*)d_out;
    float* parts = (float*)d_ws;                                  // 64 floats
    unsigned* tp8 = (unsigned*)((char*)d_ws + 4096);              // 256 KB i8 packed trans
    float* em_den = (float*)((char*)d_ws + 4096 + 262144);        // 26.2 MB
    float* em_num = em_den + 6553600;                             // 6.5 MB

    prep<<<8064, 1024, 0, stream>>>(den_trans, tp8, x, den_pdf, num_pdf, em_den, em_num);
    fwd_kernel<<<36, 1024, 0, stream>>>(seqlen, num_trans, num_init, num_final,
                                        tp8, den_init, den_final, em_den, em_num, parts);
    finish<<<1, 64, 0, stream>>>(parts, out);
}

// Round 3
// 414.450 us; speedup vs baseline: 1.3547x; 1.3547x over previous
//
#include <hip/hip_runtime.h>

#define B_ 32
#define T_ 400
#define C_ 3000
#define SN_ 128
#define SD_ 512
#define LNS 8.94637462f    // ln(64*120)
#define LN120 4.78749174f  // ln(120)
#define SPAN 80            // byte stride between 64-byte spans in LDS (bank spread)

__device__ __forceinline__ float clip30(float v) { return fminf(30.f, fmaxf(-30.f, v)); }

__device__ __forceinline__ int dot4i8(unsigned a, unsigned b, int c) {
#if __has_builtin(__builtin_amdgcn_sdot4)
    return __builtin_amdgcn_sdot4((int)a, (int)b, c, false);
#else
    return c + (int)(a & 0xff) * (int)(b & 0xff)
             + (int)((a >> 8) & 0xff) * (int)((b >> 8) & 0xff)
             + (int)((a >> 16) & 0xff) * (int)((b >> 16) & 0xff)
             + (int)((a >> 24) & 0xff) * (int)((b >> 24) & 0xff);
#endif
}

template <int CTRL>
__device__ __forceinline__ int dpp_i(int v) {
    return __builtin_amdgcn_update_dpp(v, v, CTRL, 0xF, 0xF, false);
}
template <int CTRL>
__device__ __forceinline__ float fmaxdpp(float v) {
    int mv = __builtin_amdgcn_update_dpp(__float_as_int(v), __float_as_int(v), CTRL, 0xF, 0xF, false);
    return fmaxf(v, __int_as_float(mv));
}
template <int CTRL>
__device__ __forceinline__ float faddpp(float v) {
    int mv = __builtin_amdgcn_update_dpp(__float_as_int(v), __float_as_int(v), CTRL, 0xF, 0xF, false);
    return v + __int_as_float(mv);
}
// a += partner-lane's b; quad_perm xor1=0xB1 xor2=0x4E; 0x12n = xor_n (gfx950, proven R2)
template <int CTRL>
__device__ __forceinline__ float fxaddf(float a, float b) {
    int t = __builtin_amdgcn_update_dpp(__float_as_int(b), __float_as_int(b), CTRL, 0xF, 0xF, false);
    return a + __int_as_float(t);
}
__device__ __forceinline__ float swz16f(float v) {
    return __int_as_float(__builtin_amdgcn_ds_swizzle(__float_as_int(v), 0x401F));
}
// wave-wide max, VALU-only: 4 xor-DPP stages (per-16-row max) + 4 readlanes + 3 maxes.
// ~35 cyc serial vs ~230 for ds_swizzle+shfl path. Result uniform across the wave.
__device__ __forceinline__ float wavemax_fast(float v) {
    v = fmaxdpp<0x121>(v); v = fmaxdpp<0x122>(v);
    v = fmaxdpp<0x124>(v); v = fmaxdpp<0x128>(v);
    float a = __int_as_float(__builtin_amdgcn_readlane(__float_as_int(v), 0));
    float b = __int_as_float(__builtin_amdgcn_readlane(__float_as_int(v), 16));
    float c = __int_as_float(__builtin_amdgcn_readlane(__float_as_int(v), 32));
    float d = __int_as_float(__builtin_amdgcn_readlane(__float_as_int(v), 48));
    return fmaxf(fmaxf(a, b), fmaxf(c, d));
}
__device__ __forceinline__ float waveallsum(float v) {
    v = faddpp<0x121>(v); v = faddpp<0x122>(v);
    v = faddpp<0x124>(v); v = faddpp<0x128>(v);
    v = v + swz16f(v);
    v = v + __shfl_xor(v, 32, 64);
    return v;
}

// prep:
//  [0,65536) dwords: exp(den_trans) i8 (scale 64) in the per-thread dot4 layout
//    for the 8-lane-span decomposition.
//    dword o: b4=o&3, tid=(o>>2)&511, k=o>>11; reg r=4k+b4; slot m=r>>4, i=r&15;
//    g=tid>>3, j=tid&7; s_out = 8g + (m^j)  (XOR-slot for select-free butterfly);
//    bytes: s_from = 64j + 4i + by.
//    fwd reads uint4 #k at tg[(k<<9)+tid] -> tq[4k+b4]=dword o.
//  [65536,+6553600) em_den[b][t][s] pre-clipped; then em_num[b][t][s].
__global__ void prep(const float* __restrict__ dt, unsigned* __restrict__ tp8,
                     const float* __restrict__ x, const int* __restrict__ den_pdf,
                     const int* __restrict__ num_pdf,
                     float* __restrict__ em_den, float* __restrict__ em_num) {
    size_t id = (size_t)blockIdx.x * 1024 + threadIdx.x;
    if (id < 65536) {
        int o = (int)id;
        int b4 = o & 3, tid = (o >> 2) & 511, k = o >> 11;
        int r = 4 * k + b4;
        int m = r >> 4, i = r & 15;
        int g = tid >> 3, j = tid & 7;
        int s_out = 8 * g + (m ^ j);
        int s_from0 = 64 * j + 4 * i;
        unsigned wv = 0;
        #pragma unroll
        for (int by = 0; by < 4; ++by) {
            float e = __expf(dt[(s_from0 + by) * SD_ + s_out]);
            int pq = __float2int_rn(e * 64.f);
            if (pq > 127) pq = 127;
            wv |= (unsigned)pq << (8 * by);
        }
        tp8[o] = wv;
    } else if (id < 65536 + 6553600) {
        size_t e = id - 65536;
        int s = (int)(e & 511);
        size_t bt = e >> 9;                    // b*400 + t
        em_den[e] = clip30(x[bt * C_ + den_pdf[s]]);
    } else if (id < 65536 + 6553600 + 1638400) {
        size_t e = id - 65536 - 6553600;
        int s = (int)(e & 127);
        size_t bt = e >> 7;
        int b = (int)(bt / 400);
        em_num[e] = clip30(x[bt * C_ + num_pdf[b * SN_ + s]]);
    }
}

__global__ __launch_bounds__(512, 2)
void fwd_kernel(const int* __restrict__ seqlen,
                const float* __restrict__ num_trans,
                const float* __restrict__ num_init, const float* __restrict__ num_final,
                const unsigned* __restrict__ tp8,
                const float* __restrict__ den_init, const float* __restrict__ den_final,
                const float* __restrict__ em_den, const float* __restrict__ em_num,
                float* __restrict__ parts) {
    const int tid = threadIdx.x;

    if (blockIdx.x < B_) {
        // ---- denominator: one batch/WG, 512 threads, 1 state/thread.
        // Per-wave log-scales Ms[w]; one barrier/step. 8-lane span decomposition;
        // fold is pure XOR-DPP (0xB1, 0x4E, 0x124); wave max is DPP+readlane
        // (no LDS-pipe ops anywhere in the per-step serial tail). ----
        __shared__ __align__(16) unsigned char ea[2][8 * SPAN];   // u8 activations, dbuf
        __shared__ float Ms[2][8];                                // per-wave log scales
        __shared__ float fr[8];
        const int b = blockIdx.x;
        const int L = seqlen[b];
        const int w = tid >> 6, l = tid & 63;   // wave, lane
        const int j = tid & 7;                  // source span (0..7)

        // trans: slot m, dword i -> tq[16m+i] = T8[64j+4i+b, 8g+(m^j)], pinned
        unsigned tq[128];
        {
            const uint4* tg = (const uint4*)tp8;
            #pragma unroll
            for (int i = 0; i < 32; ++i) {
                uint4 v = tg[(i << 9) + tid];
                asm volatile("v_mov_b32 %0, %1" : "=v"(tq[4 * i + 0]) : "v"(v.x));
                asm volatile("v_mov_b32 %0, %1" : "=v"(tq[4 * i + 1]) : "v"(v.y));
                asm volatile("v_mov_b32 %0, %1" : "=v"(tq[4 * i + 2]) : "v"(v.z));
                asm volatile("v_mov_b32 %0, %1" : "=v"(tq[4 * i + 3]) : "v"(v.w));
            }
        }

        const float* emp = em_den + (size_t)b * T_ * SD_ + tid;

        // t = 0: alpha0 = init + em0; quantize vs wave-local max
        float a0f = den_init[tid] + emp[0];
        float ms_w = wavemax_fast(a0f);          // own wave's scale, kept in register
        int un = __float2int_rn(fminf(120.f * __expf(a0f - ms_w), 127.f));
        {
            int uu = un;
            uu |= dpp_i<0xB1>(uu) << 8;
            uu |= dpp_i<0x4E>(uu) << 16;
            if ((tid & 3) == 0)
                *(unsigned*)&ea[0][SPAN * w + (tid & 63)] = (unsigned)uu;
        }
        if (l == 0) Ms[0][w] = ms_w;
        __syncthreads();

        float emA = emp[SD_], emB = emp[2 * SD_];
        int cur = 0;
        for (int t = 1; t < L; ++t) {
            int tn = (t + 2 < L) ? t + 2 : L - 1;
            float emN = emp[(size_t)tn * SD_];

            float ms_j = Ms[cur][j];            // source span's scale (LDS; own in reg)
            const uint4* er = (const uint4*)&ea[cur][SPAN * j];
            uint4 e0 = er[0], e1 = er[1], e2 = er[2], e3 = er[3];

            // accumulators initialized by the first dot (c = 0)
            int ac0, ac1, ac2, ac3, ac4, ac5, ac6, ac7;
            #define DOTD0(W, I) \
                ac0 = dot4i8((W), tq[(I)],       0); \
                ac1 = dot4i8((W), tq[16 + (I)],  0); \
                ac2 = dot4i8((W), tq[32 + (I)],  0); \
                ac3 = dot4i8((W), tq[48 + (I)],  0); \
                ac4 = dot4i8((W), tq[64 + (I)],  0); \
                ac5 = dot4i8((W), tq[80 + (I)],  0); \
                ac6 = dot4i8((W), tq[96 + (I)],  0); \
                ac7 = dot4i8((W), tq[112 + (I)], 0);
            #define DOTD(W, I) \
                ac0 = dot4i8((W), tq[(I)],       ac0); \
                ac1 = dot4i8((W), tq[16 + (I)],  ac1); \
                ac2 = dot4i8((W), tq[32 + (I)],  ac2); \
                ac3 = dot4i8((W), tq[48 + (I)],  ac3); \
                ac4 = dot4i8((W), tq[64 + (I)],  ac4); \
                ac5 = dot4i8((W), tq[80 + (I)],  ac5); \
                ac6 = dot4i8((W), tq[96 + (I)],  ac6); \
                ac7 = dot4i8((W), tq[112 + (I)], ac7);
            DOTD0(e0.x, 0) DOTD(e0.y, 1)  DOTD(e0.z, 2)  DOTD(e0.w, 3)
            DOTD(e1.x, 4)  DOTD(e1.y, 5)  DOTD(e1.z, 6)  DOTD(e1.w, 7)
            DOTD(e2.x, 8)  DOTD(e2.y, 9)  DOTD(e2.z, 10) DOTD(e2.w, 11)
            DOTD(e3.x, 12) DOTD(e3.y, 13) DOTD(e3.z, 14) DOTD(e3.w, 15)
            #undef DOTD
            #undef DOTD0

            // scale by own span's factor, then select-free XOR butterfly fold (all DPP)
            float e_own = __expf(ms_j - ms_w);
            float f0 = (float)ac0 * e_own, f1 = (float)ac1 * e_own;
            float f2 = (float)ac2 * e_own, f3 = (float)ac3 * e_own;
            float f4 = (float)ac4 * e_own, f5 = (float)ac5 * e_own;
            float f6 = (float)ac6 * e_own, f7 = (float)ac7 * e_own;
            f0 = fxaddf<0xB1>(f0, f1);  f2 = fxaddf<0xB1>(f2, f3);
            f4 = fxaddf<0xB1>(f4, f5);  f6 = fxaddf<0xB1>(f6, f7);
            f0 = fxaddf<0x4E>(f0, f2);  f4 = fxaddf<0x4E>(f4, f6);
            f0 = fxaddf<0x124>(f0, f4); // xor4 via DPP (proven on gfx950 by R2)

            // approx ln via float bits (underestimates <=0.06 nats; moves quant point only)
            float g = fmaf(0.69314718f,
                           (float)__float_as_int(f0) * 1.1920929e-7f - 127.0f, emA);
            float gg = wavemax_fast(g);          // VALU-only wave max
            un = __float2int_rn(fminf(120.f * f0 * __expf(emA - gg), 127.f));
            {
                int uu = un;
                uu |= dpp_i<0xB1>(uu) << 8;
                uu |= dpp_i<0x4E>(uu) << 16;
                if ((tid & 3) == 0)
                    *(unsigned*)&ea[cur ^ 1][SPAN * w + (tid & 63)] = (unsigned)uu;
            }
            ms_w = gg + ms_w - LNS;              // own next-step scale, stays in register
            if (l == 0) Ms[cur ^ 1][w] = ms_w;
            emA = emB; emB = emN;
            __syncthreads();            // single barrier per step (dbuf'd ea + Ms)
            cur ^= 1;
        }

        // final: alpha(s) = log(u_s) + Ms[w(s)] - ln120
        float mm = Ms[cur][0];
        #pragma unroll
        for (int k2 = 1; k2 < 8; ++k2) mm = fmaxf(mm, Ms[cur][k2]);
        float fv = (float)un * __expf(den_final[tid] + (ms_w - mm));
        fv = waveallsum(fv);
        if (l == 0) fr[w] = fv;
        __syncthreads();
        if (tid == 0) {
            float tot = 0.f;
            for (int i = 0; i < 8; ++i) tot += fr[i];
            parts[B_ + b] = mm + __logf(tot) - LN120;
        }
    } else {
        // ---- numerator: 4 banded 128-state chains per 512-thread WG
        //      (R1-proven path; double-buffered -> 1 barrier/step) ----
        __shared__ float aLn[2][4][SN_];
        __shared__ float nredn[4][2];
        const int nb = blockIdx.x - B_;               // 0..7
        const int lb = tid >> 7;                      // local batch 0..3
        const int b  = nb * 4 + lb;
        const int s  = tid & 127;
        const int L  = seqlen[b];
        const int lane = tid & 63;
        const int wv2 = (tid >> 6) & 1;
        const float* ep = em_num + (size_t)b * T_ * SN_ + s;
        const float tself = num_trans[((size_t)b * SN_ + s) * SN_ + s];
        const float tup = (s > 0) ? num_trans[((size_t)b * SN_ + (s - 1)) * SN_ + s] : 0.f;
        float alpha = num_init[b * SN_ + s] + ep[0];
        aLn[0][lb][s] = alpha;
        __syncthreads();
        float emA = ep[SN_], emB = ep[2 * SN_];
        int cur = 0;
        for (int t = 1; t < T_; ++t) {
            int tt = t + 2; if (tt > T_ - 1) tt = T_ - 1;
            float emN = ep[(size_t)tt * SN_];
            bool live = (t < L);
            float yy = alpha + tself;
            float newa;
            if (s > 0) {
                float xx = aLn[cur][lb][s - 1] + tup;
                float mx = fmaxf(xx, yy), mn = fminf(xx, yy);
                newa = mx + log1pf(__expf(mn - mx)) + emA;
            } else {
                newa = yy + emA;
            }
            if (live) alpha = newa;
            aLn[cur ^ 1][lb][s] = alpha;
            emA = emB; emB = emN;
            __syncthreads();
            cur ^= 1;
        }
        float v = alpha + num_final[b * SN_ + s];
        float wm = v;
        #pragma unroll
        for (int o = 32; o; o >>= 1) wm = fmaxf(wm, __shfl_xor(wm, o, 64));
        if (lane == 0) nredn[lb][wv2] = wm;
        __syncthreads();
        float fm = fmaxf(nredn[lb][0], nredn[lb][1]);
        __syncthreads();
        float pe = __expf(v - fm);
        #pragma unroll
        for (int o = 32; o; o >>= 1) pe += __shfl_xor(pe, o, 64);
        if (lane == 0) nredn[lb][wv2] = pe;
        __syncthreads();
        if (s == 0) parts[b] = fm + __logf(nredn[lb][0] + nredn[lb][1]);
    }
}

__global__ void finish(const float* __restrict__ parts, float* __restrict__ out) {
    int lane = threadIdx.x;   // 64 threads, 1 wave
    float v = (lane < B_) ? (parts[B_ + lane] - parts[lane]) : 0.f;
    #pragma unroll
    for (int o = 32; o; o >>= 1) v += __shfl_xor(v, o, 64);
    if (lane == 0) out[0] = v;   // loss = sum(den) - sum(num)
}

extern "C" void kernel_launch(void* const* d_in, const int* in_sizes, int n_in,
                              void* d_out, int out_size, void* d_ws, size_t ws_size,
                              hipStream_t stream) {
    const float* x         = (const float*)d_in[0];
    const int*   seqlen    = (const int*)d_in[1];
    const float* num_trans = (const float*)d_in[2];
    const int*   num_pdf   = (const int*)d_in[3];
    const float* num_init  = (const float*)d_in[4];
    const float* num_final = (const float*)d_in[5];
    const float* den_trans = (const float*)d_in[6];
    const int*   den_pdf   = (const int*)d_in[7];
    const float* den_init  = (const float*)d_in[8];
    const float* den_final = (const float*)d_in[9];
    float* out   = (float*)d_out;
    float* parts = (float*)d_ws;                                  // 64 floats
    unsigned* tp8 = (unsigned*)((char*)d_ws + 4096);              // 256 KB i8 packed trans
    float* em_den = (float*)((char*)d_ws + 4096 + 262144);        // 26.2 MB
    float* em_num = em_den + 6553600;                             // 6.5 MB

    prep<<<8064, 1024, 0, stream>>>(den_trans, tp8, x, den_pdf, num_pdf, em_den, em_num);
    fwd_kernel<<<40, 512, 0, stream>>>(seqlen, num_trans, num_init, num_final,
                                       tp8, den_init, den_final, em_den, em_num, parts);
    finish<<<1, 64, 0, stream>>>(parts, out);
}

// Round 4
// 409.771 us; speedup vs baseline: 1.3701x; 1.0114x over previous
//
#include <hip/hip_runtime.h>

#define B_ 32
#define T_ 400
#define C_ 3000
#define SN_ 128
#define SD_ 512
#define LNS 8.94637462f    // ln(64*120)
#define LN120 4.78749174f  // ln(120)
#define SPAN 80            // byte stride between 64-byte spans in LDS (bank spread)

__device__ __forceinline__ float clip30(float v) { return fminf(30.f, fmaxf(-30.f, v)); }

__device__ __forceinline__ int dot4i8(unsigned a, unsigned b, int c) {
#if __has_builtin(__builtin_amdgcn_sdot4)
    return __builtin_amdgcn_sdot4((int)a, (int)b, c, false);
#else
    return c + (int)(a & 0xff) * (int)(b & 0xff)
             + (int)((a >> 8) & 0xff) * (int)((b >> 8) & 0xff)
             + (int)((a >> 16) & 0xff) * (int)((b >> 16) & 0xff)
             + (int)((a >> 24) & 0xff) * (int)((b >> 24) & 0xff);
#endif
}

template <int CTRL>
__device__ __forceinline__ int dpp_i(int v) {
    return __builtin_amdgcn_update_dpp(v, v, CTRL, 0xF, 0xF, false);
}
template <int CTRL>
__device__ __forceinline__ float fmaxdpp(float v) {
    int mv = __builtin_amdgcn_update_dpp(__float_as_int(v), __float_as_int(v), CTRL, 0xF, 0xF, false);
    return fmaxf(v, __int_as_float(mv));
}
template <int CTRL>
__device__ __forceinline__ float faddpp(float v) {
    int mv = __builtin_amdgcn_update_dpp(__float_as_int(v), __float_as_int(v), CTRL, 0xF, 0xF, false);
    return v + __int_as_float(mv);
}
// a += partner-lane's b; quad_perm xor1=0xB1 xor2=0x4E; 0x12n = xor_n (gfx950, proven R2)
template <int CTRL>
__device__ __forceinline__ float fxaddf(float a, float b) {
    int t = __builtin_amdgcn_update_dpp(__float_as_int(b), __float_as_int(b), CTRL, 0xF, 0xF, false);
    return a + __int_as_float(t);
}
__device__ __forceinline__ float swz16f(float v) {
    return __int_as_float(__builtin_amdgcn_ds_swizzle(__float_as_int(v), 0x401F));
}
// wave-wide max, VALU-only: 4 xor-DPP stages (per-16-row max) + 4 readlanes + 3 maxes.
// Result uniform across the wave. (proven R3)
__device__ __forceinline__ float wavemax_fast(float v) {
    v = fmaxdpp<0x121>(v); v = fmaxdpp<0x122>(v);
    v = fmaxdpp<0x124>(v); v = fmaxdpp<0x128>(v);
    float a = __int_as_float(__builtin_amdgcn_readlane(__float_as_int(v), 0));
    float b = __int_as_float(__builtin_amdgcn_readlane(__float_as_int(v), 16));
    float c = __int_as_float(__builtin_amdgcn_readlane(__float_as_int(v), 32));
    float d = __int_as_float(__builtin_amdgcn_readlane(__float_as_int(v), 48));
    return fmaxf(fmaxf(a, b), fmaxf(c, d));
}
__device__ __forceinline__ float waveallsum(float v) {
    v = faddpp<0x121>(v); v = faddpp<0x122>(v);
    v = faddpp<0x124>(v); v = faddpp<0x128>(v);
    v = v + swz16f(v);
    v = v + __shfl_xor(v, 32, 64);
    return v;
}
// workgroup barrier with LDS-only drain: skips the conservative vmcnt(0) drain
// __syncthreads() emits, so the 2-step-ahead em prefetch stays in flight.
__device__ __forceinline__ void barrier_lds() {
    asm volatile("s_waitcnt lgkmcnt(0)\n\ts_barrier" ::: "memory");
}

// prep:
//  [0,65536) dwords: exp(den_trans) i8 (scale 64) in the per-thread dot4 layout
//    for the 8-lane-span decomposition.
//    dword o: b4=o&3, tid=(o>>2)&511, k=o>>11; reg r=4k+b4; slot m=r>>4, i=r&15;
//    g=tid>>3, j=tid&7; s_out = 8g + (m^j)  (XOR-slot for select-free butterfly);
//    bytes: s_from = 64j + 4i + by.
//    fwd reads uint4 #k at tg[(k<<9)+tid] -> tq[4k+b4]=dword o.
//  [65536,+6553600) em_den[b][t][s] pre-clipped; then em_num[b][t][s].
__global__ void prep(const float* __restrict__ dt, unsigned* __restrict__ tp8,
                     const float* __restrict__ x, const int* __restrict__ den_pdf,
                     const int* __restrict__ num_pdf,
                     float* __restrict__ em_den, float* __restrict__ em_num) {
    size_t id = (size_t)blockIdx.x * 1024 + threadIdx.x;
    if (id < 65536) {
        int o = (int)id;
        int b4 = o & 3, tid = (o >> 2) & 511, k = o >> 11;
        int r = 4 * k + b4;
        int m = r >> 4, i = r & 15;
        int g = tid >> 3, j = tid & 7;
        int s_out = 8 * g + (m ^ j);
        int s_from0 = 64 * j + 4 * i;
        unsigned wv = 0;
        #pragma unroll
        for (int by = 0; by < 4; ++by) {
            float e = __expf(dt[(s_from0 + by) * SD_ + s_out]);
            int pq = __float2int_rn(e * 64.f);
            if (pq > 127) pq = 127;
            wv |= (unsigned)pq << (8 * by);
        }
        tp8[o] = wv;
    } else if (id < 65536 + 6553600) {
        size_t e = id - 65536;
        int s = (int)(e & 511);
        size_t bt = e >> 9;                    // b*400 + t
        em_den[e] = clip30(x[bt * C_ + den_pdf[s]]);
    } else if (id < 65536 + 6553600 + 1638400) {
        size_t e = id - 65536 - 6553600;
        int s = (int)(e & 127);
        size_t bt = e >> 7;
        int b = (int)(bt / 400);
        em_num[e] = clip30(x[bt * C_ + num_pdf[b * SN_ + s]]);
    }
}

__global__ __launch_bounds__(512, 2)
void fwd_kernel(const int* __restrict__ seqlen,
                const float* __restrict__ num_trans,
                const float* __restrict__ num_init, const float* __restrict__ num_final,
                const unsigned* __restrict__ tp8,
                const float* __restrict__ den_init, const float* __restrict__ den_final,
                const float* __restrict__ em_den, const float* __restrict__ em_num,
                float* __restrict__ parts) {
    const int tid = threadIdx.x;

    if (blockIdx.x < B_) {
        // ---- denominator: one batch/WG, 512 threads, 1 state/thread.
        // Per-wave log-scales Ms[w]; one barrier/step. 8-lane span decomposition;
        // fold is pure XOR-DPP (0xB1, 0x4E, 0x124); wave max is DPP+readlane. ----
        __shared__ __align__(16) unsigned char ea[2][8 * SPAN];   // u8 activations, dbuf
        __shared__ float Ms[2][8];                                // per-wave log scales
        __shared__ float fr[8];
        const int b = blockIdx.x;
        const int L = seqlen[b];
        const int w = tid >> 6, l = tid & 63;   // wave, lane
        const int j = tid & 7;                  // source span (0..7)

        // trans: slot m, dword i -> tq[16m+i] = T8[64j+4i+b, 8g+(m^j)].
        // Plain register array (no asm pinning): 128 dwords + ~84 live others
        // fit the 256-VGPR budget of __launch_bounds__(512,2), letting dot4
        // read arch VGPRs directly instead of AGPR-parked values.
        unsigned tq[128];
        {
            const uint4* tg = (const uint4*)tp8;
            #pragma unroll
            for (int i = 0; i < 32; ++i) {
                uint4 v = tg[(i << 9) + tid];
                tq[4 * i + 0] = v.x;
                tq[4 * i + 1] = v.y;
                tq[4 * i + 2] = v.z;
                tq[4 * i + 3] = v.w;
            }
        }

        const float* emp = em_den + (size_t)b * T_ * SD_ + tid;

        // t = 0: alpha0 = init + em0; quantize vs wave-local max
        float a0f = den_init[tid] + emp[0];
        float ms_w = wavemax_fast(a0f);          // own wave's scale, kept in register
        int un = __float2int_rn(fminf(120.f * __expf(a0f - ms_w), 127.f));
        {
            int uu = un;
            uu |= dpp_i<0xB1>(uu) << 8;
            uu |= dpp_i<0x4E>(uu) << 16;
            if ((tid & 3) == 0)
                *(unsigned*)&ea[0][SPAN * w + (tid & 63)] = (unsigned)uu;
        }
        if (l == 0) Ms[0][w] = ms_w;
        barrier_lds();

        float emA = emp[SD_], emB = emp[2 * SD_];
        int cur = 0;
        for (int t = 1; t < L; ++t) {
            int tn = (t + 2 < L) ? t + 2 : L - 1;
            float emN = emp[(size_t)tn * SD_];

            float ms_j = Ms[cur][j];            // source span's scale (LDS; own in reg)
            const uint4* er = (const uint4*)&ea[cur][SPAN * j];
            uint4 e0 = er[0], e1 = er[1], e2 = er[2], e3 = er[3];

            // accumulators initialized by the first dot (c = 0)
            int ac0, ac1, ac2, ac3, ac4, ac5, ac6, ac7;
            #define DOTD0(W, I) \
                ac0 = dot4i8((W), tq[(I)],       0); \
                ac1 = dot4i8((W), tq[16 + (I)],  0); \
                ac2 = dot4i8((W), tq[32 + (I)],  0); \
                ac3 = dot4i8((W), tq[48 + (I)],  0); \
                ac4 = dot4i8((W), tq[64 + (I)],  0); \
                ac5 = dot4i8((W), tq[80 + (I)],  0); \
                ac6 = dot4i8((W), tq[96 + (I)],  0); \
                ac7 = dot4i8((W), tq[112 + (I)], 0);
            #define DOTD(W, I) \
                ac0 = dot4i8((W), tq[(I)],       ac0); \
                ac1 = dot4i8((W), tq[16 + (I)],  ac1); \
                ac2 = dot4i8((W), tq[32 + (I)],  ac2); \
                ac3 = dot4i8((W), tq[48 + (I)],  ac3); \
                ac4 = dot4i8((W), tq[64 + (I)],  ac4); \
                ac5 = dot4i8((W), tq[80 + (I)],  ac5); \
                ac6 = dot4i8((W), tq[96 + (I)],  ac6); \
                ac7 = dot4i8((W), tq[112 + (I)], ac7);
            DOTD0(e0.x, 0) DOTD(e0.y, 1)  DOTD(e0.z, 2)  DOTD(e0.w, 3)
            DOTD(e1.x, 4)  DOTD(e1.y, 5)  DOTD(e1.z, 6)  DOTD(e1.w, 7)
            DOTD(e2.x, 8)  DOTD(e2.y, 9)  DOTD(e2.z, 10) DOTD(e2.w, 11)
            DOTD(e3.x, 12) DOTD(e3.y, 13) DOTD(e3.z, 14) DOTD(e3.w, 15)
            #undef DOTD
            #undef DOTD0

            // scale by own span's factor, then select-free XOR butterfly fold (all DPP)
            float e_own = __expf(ms_j - ms_w);
            float f0 = (float)ac0 * e_own, f1 = (float)ac1 * e_own;
            float f2 = (float)ac2 * e_own, f3 = (float)ac3 * e_own;
            float f4 = (float)ac4 * e_own, f5 = (float)ac5 * e_own;
            float f6 = (float)ac6 * e_own, f7 = (float)ac7 * e_own;
            f0 = fxaddf<0xB1>(f0, f1);  f2 = fxaddf<0xB1>(f2, f3);
            f4 = fxaddf<0xB1>(f4, f5);  f6 = fxaddf<0xB1>(f6, f7);
            f0 = fxaddf<0x4E>(f0, f2);  f4 = fxaddf<0x4E>(f4, f6);
            f0 = fxaddf<0x124>(f0, f4); // xor4 via DPP (proven on gfx950 by R2)

            // approx ln via float bits (underestimates <=0.06 nats; moves quant point only)
            float g = fmaf(0.69314718f,
                           (float)__float_as_int(f0) * 1.1920929e-7f - 127.0f, emA);
            float gg = wavemax_fast(g);          // VALU-only wave max
            un = __float2int_rn(fminf(120.f * f0 * __expf(emA - gg), 127.f));
            {
                int uu = un;
                uu |= dpp_i<0xB1>(uu) << 8;
                uu |= dpp_i<0x4E>(uu) << 16;
                if ((tid & 3) == 0)
                    *(unsigned*)&ea[cur ^ 1][SPAN * w + (tid & 63)] = (unsigned)uu;
            }
            ms_w = gg + ms_w - LNS;              // own next-step scale, stays in register
            if (l == 0) Ms[cur ^ 1][w] = ms_w;
            emA = emB; emB = emN;
            barrier_lds();              // single barrier/step, LDS-drain only
            cur ^= 1;
        }

        // final: alpha(s) = log(u_s) + Ms[w(s)] - ln120
        float mm = Ms[cur][0];
        #pragma unroll
        for (int k2 = 1; k2 < 8; ++k2) mm = fmaxf(mm, Ms[cur][k2]);
        float fv = (float)un * __expf(den_final[tid] + (ms_w - mm));
        fv = waveallsum(fv);
        if (l == 0) fr[w] = fv;
        __syncthreads();
        if (tid == 0) {
            float tot = 0.f;
            for (int i = 0; i < 8; ++i) tot += fr[i];
            parts[B_ + b] = mm + __logf(tot) - LN120;
        }
    } else {
        // ---- numerator: 4 banded 128-state chains per 512-thread WG
        //      (R1-proven path; double-buffered -> 1 barrier/step) ----
        __shared__ float aLn[2][4][SN_];
        __shared__ float nredn[4][2];
        const int nb = blockIdx.x - B_;               // 0..7
        const int lb = tid >> 7;                      // local batch 0..3
        const int b  = nb * 4 + lb;
        const int s  = tid & 127;
        const int L  = seqlen[b];
        const int lane = tid & 63;
        const int wv2 = (tid >> 6) & 1;
        const float* ep = em_num + (size_t)b * T_ * SN_ + s;
        const float tself = num_trans[((size_t)b * SN_ + s) * SN_ + s];
        const float tup = (s > 0) ? num_trans[((size_t)b * SN_ + (s - 1)) * SN_ + s] : 0.f;
        float alpha = num_init[b * SN_ + s] + ep[0];
        aLn[0][lb][s] = alpha;
        __syncthreads();
        float emA = ep[SN_], emB = ep[2 * SN_];
        int cur = 0;
        for (int t = 1; t < T_; ++t) {
            int tt = t + 2; if (tt > T_ - 1) tt = T_ - 1;
            float emN = ep[(size_t)tt * SN_];
            bool live = (t < L);
            float yy = alpha + tself;
            float newa;
            if (s > 0) {
                float xx = aLn[cur][lb][s - 1] + tup;
                float mx = fmaxf(xx, yy), mn = fminf(xx, yy);
                newa = mx + log1pf(__expf(mn - mx)) + emA;
            } else {
                newa = yy + emA;
            }
            if (live) alpha = newa;
            aLn[cur ^ 1][lb][s] = alpha;
            emA = emB; emB = emN;
            __syncthreads();
            cur ^= 1;
        }
        float v = alpha + num_final[b * SN_ + s];
        float wm = v;
        #pragma unroll
        for (int o = 32; o; o >>= 1) wm = fmaxf(wm, __shfl_xor(wm, o, 64));
        if (lane == 0) nredn[lb][wv2] = wm;
        __syncthreads();
        float fm = fmaxf(nredn[lb][0], nredn[lb][1]);
        __syncthreads();
        float pe = __expf(v - fm);
        #pragma unroll
        for (int o = 32; o; o >>= 1) pe += __shfl_xor(pe, o, 64);
        if (lane == 0) nredn[lb][wv2] = pe;
        __syncthreads();
        if (s == 0) parts[b] = fm + __logf(nredn[lb][0] + nredn[lb][1]);
    }
}

__global__ void finish(const float* __restrict__ parts, float* __restrict__ out) {
    int lane = threadIdx.x;   // 64 threads, 1 wave
    float v = (lane < B_) ? (parts[B_ + lane] - parts[lane]) : 0.f;
    #pragma unroll
    for (int o = 32; o; o >>= 1) v += __shfl_xor(v, o, 64);
    if (lane == 0) out[0] = v;   // loss = sum(den) - sum(num)
}

extern "C" void kernel_launch(void* const* d_in, const int* in_sizes, int n_in,
                              void* d_out, int out_size, void* d_ws, size_t ws_size,
                              hipStream_t stream) {
    const float* x         = (const float*)d_in[0];
    const int*   seqlen    = (const int*)d_in[1];
    const float* num_trans = (const float*)d_in[2];
    const int*   num_pdf   = (const int*)d_in[3];
    const float* num_init  = (const float*)d_in[4];
    const float* num_final = (const float*)d_in[5];
    const float* den_trans = (const float*)d_in[6];
    const int*   den_pdf   = (const int*)d_in[7];
    const float* den_init  = (const float*)d_in[8];
    const float* den_final = (const float*)d_in[9];
    float* out   = (float*)d_out;
    float* parts = (float*)d_ws;                                  // 64 floats
    unsigned* tp8 = (unsigned*)((char*)d_ws + 4096);              // 256 KB i8 packed trans
    float* em_den = (float*)((char*)d_ws + 4096 + 262144);        // 26.2 MB
    float* em_num = em_den + 6553600;                             // 6.5 MB

    prep<<<8064, 1024, 0, stream>>>(den_trans, tp8, x, den_pdf, num_pdf, em_den, em_num);
    fwd_kernel<<<40, 512, 0, stream>>>(seqlen, num_trans, num_init, num_final,
                                       tp8, den_init, den_final, em_den, em_num, parts);
    finish<<<1, 64, 0, stream>>>(parts, out);
}